// Round 3
// baseline (516.275 us; speedup 1.0000x reference)
//
#include <hip/hip_runtime.h>
#include <hip/hip_bf16.h>
#include <cstdint>

typedef __attribute__((ext_vector_type(8))) short short8;
typedef __attribute__((ext_vector_type(4))) float floatx4;

#define NC   5
#define PP   196
#define DD   384
#define MM   512
#define ROWS (MM * PP)     /* 100352 = 1568 * 64 exactly */
#define NRB  1568
#define EPSN 1e-12f
#define ASTR 392           /* As row stride (bf16): 784 B -> 2-way bank aliasing only (free) */

/* swizzled B: [class 5][tile 4][kk 12][ct 4][64 lanes * 16 B]  (per class 256 cols, col>=196 replicates col 195) */
#define TILE_BYTES  49152   /* 12 * 4 * 1024 */
#define KSTEP_BYTES 4096

/* monotone float <-> uint encoding so atomicMax(unsigned) orders like float */
__device__ __forceinline__ unsigned enc_f(float f) {
    unsigned u = __float_as_uint(f);
    return (u & 0x80000000u) ? ~u : (u | 0x80000000u);
}
__device__ __forceinline__ float dec_f(unsigned u) {
    unsigned b = (u & 0x80000000u) ? (u ^ 0x80000000u) : ~u;
    return __uint_as_float(b);
}
#define ENC_NEG_INF 0x007FFFFFu

/* ---- pass 1a: 1/||support_row|| (980 rows) ---- */
__global__ __launch_bounds__(256) void k_norm0(const float* __restrict__ sup,
                                               float* __restrict__ sinv) {
    int wid = threadIdx.x >> 6, lane = threadIdx.x & 63;
    int r = blockIdx.x * 4 + wid;
    if (r >= NC * PP) return;
    const float* src = sup + (size_t)r * DD;
    float s = 0.f;
    #pragma unroll
    for (int j = 0; j < 6; ++j) { float v = src[lane + j * 64]; s += v * v; }
    #pragma unroll
    for (int off = 1; off < 64; off <<= 1) s += __shfl_xor(s, off, 64);
    if (lane == 0) sinv[r] = 1.0f / fmaxf(sqrtf(s), EPSN);
}

/* ---- pass 1b: normalize + swizzle support into MFMA B-fragment order ---- */
__global__ __launch_bounds__(256) void k_swz(const float* __restrict__ sup,
                                             const float* __restrict__ sinv,
                                             __hip_bfloat16* __restrict__ snw) {
    int s = blockIdx.x * 256 + threadIdx.x;       /* 61440 slices of 16 B */
    int lane = s & 63;
    int r1 = s >> 6;
    int ct = r1 & 3;
    int r2 = r1 >> 2;
    int kk = r2 % 12;
    int g  = r2 / 12;                              /* 0..19 = class*4 + tile */
    int c = g >> 2, t = g & 3;
    int c16 = lane & 15, quad = lane >> 4;
    int cl = t * 64 + ct * 16 + c16;               /* class-local padded col */
    if (cl > PP - 1) cl = PP - 1;                  /* replicate last col: max-invariant */
    int srow = c * PP + cl;
    const float* sp = sup + (size_t)srow * DD + kk * 32 + quad * 8;
    float inv = sinv[srow];
    alignas(16) __hip_bfloat16 hb[8];
    #pragma unroll
    for (int e = 0; e < 8; ++e) hb[e] = __float2bfloat16(sp[e] * inv);
    *(uint4*)((char*)snw + (size_t)s * 16) = *(const uint4*)hb;
}

/* ---- main: one block per 64-row strip; A bf16 resident in LDS (one barrier);
        waves stream B-frags straight from L2 (pre-swizzled), NO barriers in loop ---- */
__global__ __launch_bounds__(256, 3) void k_gemm_max(const float* __restrict__ q,
                                                     const __hip_bfloat16* __restrict__ snw,
                                                     float* __restrict__ rowmaxg) {
    __shared__ __hip_bfloat16 As[64 * ASTR];    /* 50176 B */
    __shared__ unsigned rmax[64 * NC];          /*  1280 B */
    __shared__ float rss[64];                   /*   256 B */

    const int tid  = threadIdx.x;
    const int row0 = blockIdx.x * 64;
    const int lane = tid & 63;
    const int wav  = tid >> 6;
    const int quad = lane >> 4, c16 = lane & 15;

    for (int i = tid; i < 64 * NC; i += 256) rmax[i] = ENC_NEG_INF;

    /* ---- A staging: fp32 -> bf16 into LDS, fused row sum-of-squares ---- */
    {
        const int arow = tid >> 2;              /* 0..63 */
        const int asub = tid & 3;
        const float* src = q + (size_t)(row0 + arow) * DD;
        float ss = 0.f;
        #pragma unroll
        for (int i = 0; i < 12; ++i) {
            int ch = asub + i * 4;              /* chunk of 8 elems */
            const float4* p = (const float4*)(src + ch * 8);
            float4 x0 = p[0], x1 = p[1];
            ss += x0.x*x0.x + x0.y*x0.y + x0.z*x0.z + x0.w*x0.w
                + x1.x*x1.x + x1.y*x1.y + x1.z*x1.z + x1.w*x1.w;
            alignas(16) __hip_bfloat16 hb[8];
            hb[0] = __float2bfloat16(x0.x); hb[1] = __float2bfloat16(x0.y);
            hb[2] = __float2bfloat16(x0.z); hb[3] = __float2bfloat16(x0.w);
            hb[4] = __float2bfloat16(x1.x); hb[5] = __float2bfloat16(x1.y);
            hb[6] = __float2bfloat16(x1.z); hb[7] = __float2bfloat16(x1.w);
            *(uint4*)&As[arow * ASTR + ch * 8] = *(const uint4*)hb;
        }
        ss += __shfl_xor(ss, 1, 64);
        ss += __shfl_xor(ss, 2, 64);
        if (asub == 0) rss[arow] = ss;
    }
    __syncthreads();                            /* the ONLY barrier before the epilogue */

    /* ---- 20 col-tiles (class c = g>>2), 5 per wave; K pipelined by 2 ---- */
    #pragma unroll 1
    for (int g = wav; g < 20; g += 4) {
        floatx4 acc[4][4];
        #pragma unroll
        for (int i = 0; i < 4; ++i)
            #pragma unroll
            for (int j = 0; j < 4; ++j) acc[i][j] = (floatx4){0.f, 0.f, 0.f, 0.f};

        const char* bbase = (const char*)snw + (size_t)g * TILE_BYTES + (size_t)lane * 16;
        short8 b0[4], b1[4], a[4];
        #pragma unroll
        for (int ct = 0; ct < 4; ++ct) b0[ct] = ((const short8*)bbase)[ct * 64];

        #pragma unroll
        for (int kk = 0; kk < 12; kk += 2) {
            /* prefetch kk+1 */
            #pragma unroll
            for (int ct = 0; ct < 4; ++ct)
                b1[ct] = ((const short8*)(bbase + (kk + 1) * KSTEP_BYTES))[ct * 64];
            #pragma unroll
            for (int rt = 0; rt < 4; ++rt)
                a[rt] = *(const short8*)&As[(rt * 16 + c16) * ASTR + kk * 32 + quad * 8];
            #pragma unroll
            for (int rt = 0; rt < 4; ++rt)
                #pragma unroll
                for (int ct = 0; ct < 4; ++ct)
                    acc[rt][ct] = __builtin_amdgcn_mfma_f32_16x16x32_bf16(
                        a[rt], b0[ct], acc[rt][ct], 0, 0, 0);
            /* prefetch kk+2 */
            if (kk + 2 < 12) {
                #pragma unroll
                for (int ct = 0; ct < 4; ++ct)
                    b0[ct] = ((const short8*)(bbase + (kk + 2) * KSTEP_BYTES))[ct * 64];
            }
            #pragma unroll
            for (int rt = 0; rt < 4; ++rt)
                a[rt] = *(const short8*)&As[(rt * 16 + c16) * ASTR + (kk + 1) * 32 + quad * 8];
            #pragma unroll
            for (int rt = 0; rt < 4; ++rt)
                #pragma unroll
                for (int ct = 0; ct < 4; ++ct)
                    acc[rt][ct] = __builtin_amdgcn_mfma_f32_16x16x32_bf16(
                        a[rt], b1[ct], acc[rt][ct], 0, 0, 0);
        }

        /* ---- epilogue: col-max (no masking needed; padded cols are replicas) ---- */
        const int c = g >> 2;
        #pragma unroll
        for (int rt = 0; rt < 4; ++rt) {
            #pragma unroll
            for (int reg = 0; reg < 4; ++reg) {
                float mx = fmaxf(fmaxf(acc[rt][0][reg], acc[rt][1][reg]),
                                 fmaxf(acc[rt][2][reg], acc[rt][3][reg]));
                #pragma unroll
                for (int off = 1; off < 16; off <<= 1)
                    mx = fmaxf(mx, __shfl_xor(mx, off, 64));
                if (c16 == 0) {
                    int rloc = rt * 16 + quad * 4 + reg;
                    atomicMax(&rmax[rloc * NC + c], enc_f(mx));
                }
            }
        }
    }

    __syncthreads();
    for (int i = tid; i < 64 * NC; i += 256) {
        int row = i / NC, c = i % NC;
        float inv = 1.0f / fmaxf(sqrtf(rss[row]), EPSN);
        rowmaxg[(size_t)(row0 + row) * NC + c] = dec_f(rmax[row * NC + c]) * inv;
    }
}

/* ---- top-6 sum per (m, c): one wave each ---- */
__global__ __launch_bounds__(256) void k_top6(const float* __restrict__ rowmaxg,
                                              const float* __restrict__ scale,
                                              const float* __restrict__ bias,
                                              float* __restrict__ out) {
    int wav = threadIdx.x >> 6, lane = threadIdx.x & 63;
    int pair = blockIdx.x * 4 + wav;
    if (pair >= MM * NC) return;
    int m = pair / NC, c = pair % NC;
    size_t base = (size_t)m * PP;
    float v[4];
    #pragma unroll
    for (int i = 0; i < 4; ++i) {
        int p = lane + i * 64;
        v[i] = (p < PP) ? rowmaxg[(base + p) * NC + c] : -INFINITY;
    }
    float sum = 0.f;
    for (int t = 0; t < 6; ++t) {
        float bv = v[0]; int bi = 0;
        #pragma unroll
        for (int i = 1; i < 4; ++i) { if (v[i] > bv) { bv = v[i]; bi = i; } }
        int gid = bi * 64 + lane;
        #pragma unroll
        for (int off = 1; off < 64; off <<= 1) {
            float ov = __shfl_xor(bv, off, 64);
            int og  = __shfl_xor(gid, off, 64);
            if (ov > bv || (ov == bv && og < gid)) { bv = ov; gid = og; }
        }
        sum += bv;
        if ((gid & 63) == lane) v[gid >> 6] = -INFINITY;  /* kill exactly one */
    }
    if (lane == 0) out[pair] = scale[0] * (sum + bias[0]);
}

extern "C" void kernel_launch(void* const* d_in, const int* in_sizes, int n_in,
                              void* d_out, int out_size, void* d_ws, size_t ws_size,
                              hipStream_t stream) {
    const float* support = (const float*)d_in[0];
    const float* query   = (const float*)d_in[1];
    const float* scale   = (const float*)d_in[2];
    const float* bias    = (const float*)d_in[3];
    float* out = (float*)d_out;

    char* ws = (char*)d_ws;
    __hip_bfloat16* snw = (__hip_bfloat16*)ws;             /* 5*4*12*4*1024 = 983040 B */
    float* sinv         = (float*)(ws + 983040);           /* 980*4 -> pad to 4096 */
    float* rowmaxg      = (float*)(ws + 983040 + 4096);    /* 100352*5*4 = 2007040 */

    hipLaunchKernelGGL(k_norm0,   dim3(245),  dim3(256), 0, stream, support, sinv);
    hipLaunchKernelGGL(k_swz,     dim3(240),  dim3(256), 0, stream, support, sinv, snw);
    hipLaunchKernelGGL(k_gemm_max,dim3(NRB),  dim3(256), 0, stream, query, snw, rowmaxg);
    hipLaunchKernelGGL(k_top6,    dim3(640),  dim3(256), 0, stream, rowmaxg, scale, bias, out);
}

// Round 5
// 326.104 us; speedup vs baseline: 1.5832x; 1.5832x over previous
//
#include <hip/hip_runtime.h>
#include <hip/hip_bf16.h>
#include <cstdint>

typedef __attribute__((ext_vector_type(8))) short short8;
typedef __attribute__((ext_vector_type(4))) float floatx4;

#define NC   5
#define PP   196
#define DD   384
#define MM   512
#define ROWS (MM * PP)     /* 100352 = 1568 * 64 exactly */
#define NRB  1568
#define EPSN 1e-12f
#define ASTR 392           /* As row stride (bf16): 784 B -> 2-way bank aliasing only (free) */

/* swizzled B: [class 5][tile 4][kk 12][ct 4][64 lanes * 16 B]  (per class 256 cols, col>=196 replicates col 195) */
#define TILE_BYTES  49152   /* 12 * 4 * 1024 */
#define KSTEP_BYTES 4096

/* monotone float <-> uint encoding so atomicMax(unsigned) orders like float */
__device__ __forceinline__ unsigned enc_f(float f) {
    unsigned u = __float_as_uint(f);
    return (u & 0x80000000u) ? ~u : (u | 0x80000000u);
}
__device__ __forceinline__ float dec_f(unsigned u) {
    unsigned b = (u & 0x80000000u) ? (u ^ 0x80000000u) : ~u;
    return __uint_as_float(b);
}
#define ENC_NEG_INF 0x007FFFFFu

/* ---- pass 1a: 1/||support_row|| (980 rows) ---- */
__global__ __launch_bounds__(256) void k_norm0(const float* __restrict__ sup,
                                               float* __restrict__ sinv) {
    int wid = threadIdx.x >> 6, lane = threadIdx.x & 63;
    int r = blockIdx.x * 4 + wid;
    if (r >= NC * PP) return;
    const float* src = sup + (size_t)r * DD;
    float s = 0.f;
    #pragma unroll
    for (int j = 0; j < 6; ++j) { float v = src[lane + j * 64]; s += v * v; }
    #pragma unroll
    for (int off = 1; off < 64; off <<= 1) s += __shfl_xor(s, off, 64);
    if (lane == 0) sinv[r] = 1.0f / fmaxf(sqrtf(s), EPSN);
}

/* ---- pass 1b: normalize + swizzle support into MFMA B-fragment order ---- */
__global__ __launch_bounds__(256) void k_swz(const float* __restrict__ sup,
                                             const float* __restrict__ sinv,
                                             __hip_bfloat16* __restrict__ snw) {
    int s = blockIdx.x * 256 + threadIdx.x;       /* 61440 slices of 16 B */
    int lane = s & 63;
    int r1 = s >> 6;
    int ct = r1 & 3;
    int r2 = r1 >> 2;
    int kk = r2 % 12;
    int g  = r2 / 12;                              /* 0..19 = class*4 + tile */
    int c = g >> 2, t = g & 3;
    int c16 = lane & 15, quad = lane >> 4;
    int cl = t * 64 + ct * 16 + c16;               /* class-local padded col */
    if (cl > PP - 1) cl = PP - 1;                  /* replicate last col: max-invariant */
    int srow = c * PP + cl;
    const float* sp = sup + (size_t)srow * DD + kk * 32 + quad * 8;
    float inv = sinv[srow];
    alignas(16) __hip_bfloat16 hb[8];
    #pragma unroll
    for (int e = 0; e < 8; ++e) hb[e] = __float2bfloat16(sp[e] * inv);
    *(uint4*)((char*)snw + (size_t)s * 16) = *(const uint4*)hb;
}

/* ---- main: one block per 64-row strip; A bf16 resident in LDS (one barrier);
        waves stream B-frags straight from L2 (pre-swizzled), NO barriers in loop ---- */
__global__ __launch_bounds__(256, 3) void k_gemm_max(const float* __restrict__ q,
                                                     const __hip_bfloat16* __restrict__ snw,
                                                     float* __restrict__ rowmaxg) {
    __shared__ __hip_bfloat16 As[64 * ASTR];    /* 50176 B */
    __shared__ unsigned rmax[64 * NC];          /*  1280 B */
    __shared__ float rss[64];                   /*   256 B */

    const int tid  = threadIdx.x;
    const int row0 = blockIdx.x * 64;
    const int lane = tid & 63;
    const int wav  = tid >> 6;
    const int quad = lane >> 4, c16 = lane & 15;

    for (int i = tid; i < 64 * NC; i += 256) rmax[i] = ENC_NEG_INF;

    /* ---- A staging: fp32 -> bf16 into LDS, fused row sum-of-squares.
            Non-temporal: query is streamed once, must not evict B from L2. ---- */
    {
        const int arow = tid >> 2;              /* 0..63 */
        const int asub = tid & 3;
        const float* src = q + (size_t)(row0 + arow) * DD;
        float ss = 0.f;
        #pragma unroll
        for (int i = 0; i < 12; ++i) {
            int ch = asub + i * 4;              /* chunk of 8 elems */
            const floatx4* p = (const floatx4*)(src + ch * 8);
            floatx4 x0 = __builtin_nontemporal_load(p);
            floatx4 x1 = __builtin_nontemporal_load(p + 1);
            ss += x0.x*x0.x + x0.y*x0.y + x0.z*x0.z + x0.w*x0.w
                + x1.x*x1.x + x1.y*x1.y + x1.z*x1.z + x1.w*x1.w;
            alignas(16) __hip_bfloat16 hb[8];
            hb[0] = __float2bfloat16(x0.x); hb[1] = __float2bfloat16(x0.y);
            hb[2] = __float2bfloat16(x0.z); hb[3] = __float2bfloat16(x0.w);
            hb[4] = __float2bfloat16(x1.x); hb[5] = __float2bfloat16(x1.y);
            hb[6] = __float2bfloat16(x1.z); hb[7] = __float2bfloat16(x1.w);
            *(uint4*)&As[arow * ASTR + ch * 8] = *(const uint4*)hb;
        }
        ss += __shfl_xor(ss, 1, 64);
        ss += __shfl_xor(ss, 2, 64);
        if (asub == 0) rss[arow] = ss;
    }
    __syncthreads();                            /* the ONLY barrier before the epilogue */

    /* ---- 20 col-tiles (class c = g>>2), 5 per wave; K pipelined by 2.
            NOTE: kk loop must stay rolled (#pragma unroll 1) — full unroll hoists
            all B loads, explodes live ranges, and spills to scratch (R3: 227 MB
            of scratch writes). ---- */
    #pragma unroll 1
    for (int g = wav; g < 20; g += 4) {
        floatx4 acc[4][4];
        #pragma unroll
        for (int i = 0; i < 4; ++i)
            #pragma unroll
            for (int j = 0; j < 4; ++j) acc[i][j] = (floatx4){0.f, 0.f, 0.f, 0.f};

        const char* bbase = (const char*)snw + (size_t)g * TILE_BYTES + (size_t)lane * 16;
        short8 b0[4], b1[4], a[4];
        #pragma unroll
        for (int ct = 0; ct < 4; ++ct) b0[ct] = ((const short8*)bbase)[ct * 64];

        #pragma unroll 1
        for (int kk = 0; kk < 12; kk += 2) {
            /* prefetch kk+1 */
            #pragma unroll
            for (int ct = 0; ct < 4; ++ct)
                b1[ct] = ((const short8*)(bbase + (kk + 1) * KSTEP_BYTES))[ct * 64];
            #pragma unroll
            for (int rt = 0; rt < 4; ++rt)
                a[rt] = *(const short8*)&As[(rt * 16 + c16) * ASTR + kk * 32 + quad * 8];
            #pragma unroll
            for (int rt = 0; rt < 4; ++rt)
                #pragma unroll
                for (int ct = 0; ct < 4; ++ct)
                    acc[rt][ct] = __builtin_amdgcn_mfma_f32_16x16x32_bf16(
                        a[rt], b0[ct], acc[rt][ct], 0, 0, 0);
            /* prefetch kk+2 */
            if (kk + 2 < 12) {
                #pragma unroll
                for (int ct = 0; ct < 4; ++ct)
                    b0[ct] = ((const short8*)(bbase + (kk + 2) * KSTEP_BYTES))[ct * 64];
            }
            #pragma unroll
            for (int rt = 0; rt < 4; ++rt)
                a[rt] = *(const short8*)&As[(rt * 16 + c16) * ASTR + (kk + 1) * 32 + quad * 8];
            #pragma unroll
            for (int rt = 0; rt < 4; ++rt)
                #pragma unroll
                for (int ct = 0; ct < 4; ++ct)
                    acc[rt][ct] = __builtin_amdgcn_mfma_f32_16x16x32_bf16(
                        a[rt], b1[ct], acc[rt][ct], 0, 0, 0);
        }

        /* ---- epilogue: col-max (no masking needed; padded cols are replicas) ---- */
        const int c = g >> 2;
        #pragma unroll
        for (int rt = 0; rt < 4; ++rt) {
            #pragma unroll
            for (int reg = 0; reg < 4; ++reg) {
                float mx = fmaxf(fmaxf(acc[rt][0][reg], acc[rt][1][reg]),
                                 fmaxf(acc[rt][2][reg], acc[rt][3][reg]));
                #pragma unroll
                for (int off = 1; off < 16; off <<= 1)
                    mx = fmaxf(mx, __shfl_xor(mx, off, 64));
                if (c16 == 0) {
                    int rloc = rt * 16 + quad * 4 + reg;
                    atomicMax(&rmax[rloc * NC + c], enc_f(mx));
                }
            }
        }
    }

    __syncthreads();
    for (int i = tid; i < 64 * NC; i += 256) {
        int row = i / NC, c = i % NC;
        float inv = 1.0f / fmaxf(sqrtf(rss[row]), EPSN);
        __builtin_nontemporal_store(dec_f(rmax[row * NC + c]) * inv,
                                    &rowmaxg[(size_t)(row0 + row) * NC + c]);
    }
}

/* ---- top-6 sum per (m, c): one wave each ---- */
__global__ __launch_bounds__(256) void k_top6(const float* __restrict__ rowmaxg,
                                              const float* __restrict__ scale,
                                              const float* __restrict__ bias,
                                              float* __restrict__ out) {
    int wav = threadIdx.x >> 6, lane = threadIdx.x & 63;
    int pair = blockIdx.x * 4 + wav;
    if (pair >= MM * NC) return;
    int m = pair / NC, c = pair % NC;
    size_t base = (size_t)m * PP;
    float v[4];
    #pragma unroll
    for (int i = 0; i < 4; ++i) {
        int p = lane + i * 64;
        v[i] = (p < PP) ? rowmaxg[(base + p) * NC + c] : -INFINITY;
    }
    float sum = 0.f;
    for (int t = 0; t < 6; ++t) {
        float bv = v[0]; int bi = 0;
        #pragma unroll
        for (int i = 1; i < 4; ++i) { if (v[i] > bv) { bv = v[i]; bi = i; } }
        int gid = bi * 64 + lane;
        #pragma unroll
        for (int off = 1; off < 64; off <<= 1) {
            float ov = __shfl_xor(bv, off, 64);
            int og  = __shfl_xor(gid, off, 64);
            if (ov > bv || (ov == bv && og < gid)) { bv = ov; gid = og; }
        }
        sum += bv;
        if ((gid & 63) == lane) v[gid >> 6] = -INFINITY;  /* kill exactly one */
    }
    if (lane == 0) out[pair] = scale[0] * (sum + bias[0]);
}

extern "C" void kernel_launch(void* const* d_in, const int* in_sizes, int n_in,
                              void* d_out, int out_size, void* d_ws, size_t ws_size,
                              hipStream_t stream) {
    const float* support = (const float*)d_in[0];
    const float* query   = (const float*)d_in[1];
    const float* scale   = (const float*)d_in[2];
    const float* bias    = (const float*)d_in[3];
    float* out = (float*)d_out;

    char* ws = (char*)d_ws;
    __hip_bfloat16* snw = (__hip_bfloat16*)ws;             /* 5*4*12*4*1024 = 983040 B */
    float* sinv         = (float*)(ws + 983040);           /* 980*4 -> pad to 4096 */
    float* rowmaxg      = (float*)(ws + 983040 + 4096);    /* 100352*5*4 = 2007040 */

    hipLaunchKernelGGL(k_norm0,   dim3(245),  dim3(256), 0, stream, support, sinv);
    hipLaunchKernelGGL(k_swz,     dim3(240),  dim3(256), 0, stream, support, sinv, snw);
    hipLaunchKernelGGL(k_gemm_max,dim3(NRB),  dim3(256), 0, stream, query, snw, rowmaxg);
    hipLaunchKernelGGL(k_top6,    dim3(640),  dim3(256), 0, stream, rowmaxg, scale, bias, out);
}

// Round 6
// 323.564 us; speedup vs baseline: 1.5956x; 1.0078x over previous
//
#include <hip/hip_runtime.h>
#include <hip/hip_bf16.h>
#include <cstdint>

typedef __attribute__((ext_vector_type(8))) short short8;
typedef __attribute__((ext_vector_type(4))) float floatx4;

#define NC   5
#define PP   196
#define DD   384
#define MM   512
#define ROWS (MM * PP)     /* 100352 = 1568 * 64 exactly */
#define NRB  1568
#define EPSN 1e-12f

/* swizzled B: [class 5][tile 4][kk 12][ct 4][64 lanes * 16 B]  (per class 256 cols, col>=196 replicates col 195) */
#define TILE_BYTES  49152   /* 12 * 4 * 1024 */
#define KSTEP_BYTES 4096

/* monotone float <-> uint encoding so atomicMax(unsigned) orders like float */
__device__ __forceinline__ unsigned enc_f(float f) {
    unsigned u = __float_as_uint(f);
    return (u & 0x80000000u) ? ~u : (u | 0x80000000u);
}
__device__ __forceinline__ float dec_f(unsigned u) {
    unsigned b = (u & 0x80000000u) ? (u ^ 0x80000000u) : ~u;
    return __uint_as_float(b);
}
#define ENC_NEG_INF 0x007FFFFFu

/* ---- pass 1a: 1/||support_row|| (980 rows) ---- */
__global__ __launch_bounds__(256) void k_norm0(const float* __restrict__ sup,
                                               float* __restrict__ sinv) {
    int wid = threadIdx.x >> 6, lane = threadIdx.x & 63;
    int r = blockIdx.x * 4 + wid;
    if (r >= NC * PP) return;
    const float* src = sup + (size_t)r * DD;
    float s = 0.f;
    #pragma unroll
    for (int j = 0; j < 6; ++j) { float v = src[lane + j * 64]; s += v * v; }
    #pragma unroll
    for (int off = 1; off < 64; off <<= 1) s += __shfl_xor(s, off, 64);
    if (lane == 0) sinv[r] = 1.0f / fmaxf(sqrtf(s), EPSN);
}

/* ---- pass 1b: normalize + swizzle support into MFMA B-fragment order ---- */
__global__ __launch_bounds__(256) void k_swz(const float* __restrict__ sup,
                                             const float* __restrict__ sinv,
                                             __hip_bfloat16* __restrict__ snw) {
    int s = blockIdx.x * 256 + threadIdx.x;       /* 61440 slices of 16 B */
    int lane = s & 63;
    int r1 = s >> 6;
    int ct = r1 & 3;
    int r2 = r1 >> 2;
    int kk = r2 % 12;
    int g  = r2 / 12;                              /* 0..19 = class*4 + tile */
    int c = g >> 2, t = g & 3;
    int c16 = lane & 15, quad = lane >> 4;
    int cl = t * 64 + ct * 16 + c16;               /* class-local padded col */
    if (cl > PP - 1) cl = PP - 1;                  /* replicate last col: max-invariant */
    int srow = c * PP + cl;
    const float* sp = sup + (size_t)srow * DD + kk * 32 + quad * 8;
    float inv = sinv[srow];
    alignas(16) __hip_bfloat16 hb[8];
    #pragma unroll
    for (int e = 0; e < 8; ++e) hb[e] = __float2bfloat16(sp[e] * inv);
    *(uint4*)((char*)snw + (size_t)s * 16) = *(const uint4*)hb;
}

/* ---- main: one block per 64-row strip; A in LDS in MFMA FRAGMENT ORDER
        (conflict-free ds_read_b128); waves stream B from L2, depth-3 pipeline
        with cross-tile prefetch; NO barriers in the main loop ---- */
__global__ __launch_bounds__(256, 3) void k_gemm_max(const float* __restrict__ q,
                                                     const __hip_bfloat16* __restrict__ snw,
                                                     float* __restrict__ rowmaxg) {
    /* As fragment order: [kk 12][rt 4][lane 64][8 bf16] = 49152 B */
    __shared__ __hip_bfloat16 As[12 * 4 * 64 * 8];
    __shared__ unsigned rmax[64 * NC];
    __shared__ float rss[64];

    const int tid  = threadIdx.x;
    const int row0 = blockIdx.x * 64;
    const int lane = tid & 63;
    const int wav  = tid >> 6;

    for (int i = tid; i < 64 * NC; i += 256) rmax[i] = ENC_NEG_INF;

    /* ---- A staging: fp32 -> bf16 -> LDS fragment slots; fused row sumsq.
            Thread (arow=tid>>2, ch=asub+4i) produces frag (kk=ch>>2, rt=arow>>4)
            lane (ch&3)*16+(arow&15). Non-temporal: query must not evict B from L2. */
    {
        const int arow = tid >> 2;
        const int asub = tid & 3;
        const int rt   = arow >> 4, c16 = arow & 15;
        const float* src = q + (size_t)(row0 + arow) * DD;
        float ss = 0.f;
        #pragma unroll
        for (int i = 0; i < 12; ++i) {
            int ch = asub + i * 4;
            const floatx4* p = (const floatx4*)(src + ch * 8);
            floatx4 x0 = __builtin_nontemporal_load(p);
            floatx4 x1 = __builtin_nontemporal_load(p + 1);
            ss += x0.x*x0.x + x0.y*x0.y + x0.z*x0.z + x0.w*x0.w
                + x1.x*x1.x + x1.y*x1.y + x1.z*x1.z + x1.w*x1.w;
            alignas(16) __hip_bfloat16 hb[8];
            hb[0] = __float2bfloat16(x0.x); hb[1] = __float2bfloat16(x0.y);
            hb[2] = __float2bfloat16(x0.z); hb[3] = __float2bfloat16(x0.w);
            hb[4] = __float2bfloat16(x1.x); hb[5] = __float2bfloat16(x1.y);
            hb[6] = __float2bfloat16(x1.z); hb[7] = __float2bfloat16(x1.w);
            int kk = ch >> 2, quad = ch & 3;
            *(uint4*)&As[(((kk * 4 + rt) * 64) + quad * 16 + c16) * 8] = *(const uint4*)hb;
        }
        ss += __shfl_xor(ss, 1, 64);
        ss += __shfl_xor(ss, 2, 64);
        if (asub == 0) rss[arow] = ss;
    }
    __syncthreads();                            /* the ONLY barrier before the epilogue */

    /* ---- 20 col-tiles (class c = g>>2), 5 per wave; depth-3 rotating B buffers,
            loads continue across g-tiles (epilogue overlaps next tile's loads).
            kk loop stays rolled: full unroll spilled to scratch in R3 (227 MB). */
    const char* bbase = (const char*)snw + (size_t)wav * TILE_BYTES + (size_t)lane * 16;
    short8 b0[4], b1[4], b2[4], a[4];
    #pragma unroll
    for (int ct = 0; ct < 4; ++ct) b0[ct] = ((const short8*)(bbase + 0 * KSTEP_BYTES))[ct * 64];
    #pragma unroll
    for (int ct = 0; ct < 4; ++ct) b1[ct] = ((const short8*)(bbase + 1 * KSTEP_BYTES))[ct * 64];
    #pragma unroll
    for (int ct = 0; ct < 4; ++ct) b2[ct] = ((const short8*)(bbase + 2 * KSTEP_BYTES))[ct * 64];

    #define LOAD_NEXT(buf, step)                                                     \
        do {                                                                         \
            int nk = kk + 3 + (step);                                                \
            if (nk < 12) {                                                           \
                _Pragma("unroll")                                                    \
                for (int ct = 0; ct < 4; ++ct)                                       \
                    buf[ct] = ((const short8*)(bbase + nk * KSTEP_BYTES))[ct * 64];  \
            } else if (g + 4 < 20) {                                                 \
                _Pragma("unroll")                                                    \
                for (int ct = 0; ct < 4; ++ct)                                       \
                    buf[ct] = ((const short8*)(bbase + 4 * TILE_BYTES +              \
                                               (nk - 12) * KSTEP_BYTES))[ct * 64];   \
            }                                                                        \
        } while (0)

    #define MFMA_STEP(buf, kkoff)                                                    \
        do {                                                                         \
            _Pragma("unroll")                                                        \
            for (int rt = 0; rt < 4; ++rt)                                           \
                a[rt] = *(const short8*)&As[(((kk + (kkoff)) * 4 + rt) * 64 + lane) * 8]; \
            _Pragma("unroll")                                                        \
            for (int rt = 0; rt < 4; ++rt)                                           \
                _Pragma("unroll")                                                    \
                for (int ct = 0; ct < 4; ++ct)                                       \
                    acc[rt][ct] = __builtin_amdgcn_mfma_f32_16x16x32_bf16(           \
                        a[rt], buf[ct], acc[rt][ct], 0, 0, 0);                       \
        } while (0)

    #pragma unroll 1
    for (int g = wav; g < 20; g += 4) {
        floatx4 acc[4][4];
        #pragma unroll
        for (int i = 0; i < 4; ++i)
            #pragma unroll
            for (int j = 0; j < 4; ++j) acc[i][j] = (floatx4){0.f, 0.f, 0.f, 0.f};

        #pragma unroll 1
        for (int kk = 0; kk < 12; kk += 3) {
            MFMA_STEP(b0, 0); LOAD_NEXT(b0, 0);
            MFMA_STEP(b1, 1); LOAD_NEXT(b1, 1);
            MFMA_STEP(b2, 2); LOAD_NEXT(b2, 2);
        }

        /* ---- epilogue: col-max (padded cols are replicas -> no masking);
                overlaps the already-issued next-tile B loads ---- */
        const int c = g >> 2;
        const int quad = lane >> 4, c16 = lane & 15;
        #pragma unroll
        for (int rt = 0; rt < 4; ++rt) {
            #pragma unroll
            for (int reg = 0; reg < 4; ++reg) {
                float mx = fmaxf(fmaxf(acc[rt][0][reg], acc[rt][1][reg]),
                                 fmaxf(acc[rt][2][reg], acc[rt][3][reg]));
                #pragma unroll
                for (int off = 1; off < 16; off <<= 1)
                    mx = fmaxf(mx, __shfl_xor(mx, off, 64));
                if (c16 == 0) {
                    int rloc = rt * 16 + quad * 4 + reg;
                    atomicMax(&rmax[rloc * NC + c], enc_f(mx));
                }
            }
        }
        bbase += 4 * TILE_BYTES;
    }

    __syncthreads();
    /* rowmaxg layout [c][row] -> coalesced stores here, coalesced loads in k_top6 */
    for (int i = tid; i < 64 * NC; i += 256) {
        int c = i >> 6, row = i & 63;
        float inv = 1.0f / fmaxf(sqrtf(rss[row]), EPSN);
        __builtin_nontemporal_store(dec_f(rmax[row * NC + c]) * inv,
                                    &rowmaxg[(size_t)c * ROWS + row0 + row]);
    }
}

/* ---- top-6 sum per (m, c): one wave each ---- */
__global__ __launch_bounds__(256) void k_top6(const float* __restrict__ rowmaxg,
                                              const float* __restrict__ scale,
                                              const float* __restrict__ bias,
                                              float* __restrict__ out) {
    int wav = threadIdx.x >> 6, lane = threadIdx.x & 63;
    int pair = blockIdx.x * 4 + wav;
    if (pair >= MM * NC) return;
    int m = pair / NC, c = pair % NC;
    size_t base = (size_t)c * ROWS + (size_t)m * PP;
    float v[4];
    #pragma unroll
    for (int i = 0; i < 4; ++i) {
        int p = lane + i * 64;
        v[i] = (p < PP) ? rowmaxg[base + p] : -INFINITY;
    }
    float sum = 0.f;
    for (int t = 0; t < 6; ++t) {
        float bv = v[0]; int bi = 0;
        #pragma unroll
        for (int i = 1; i < 4; ++i) { if (v[i] > bv) { bv = v[i]; bi = i; } }
        int gid = bi * 64 + lane;
        #pragma unroll
        for (int off = 1; off < 64; off <<= 1) {
            float ov = __shfl_xor(bv, off, 64);
            int og  = __shfl_xor(gid, off, 64);
            if (ov > bv || (ov == bv && og < gid)) { bv = ov; gid = og; }
        }
        sum += bv;
        if ((gid & 63) == lane) v[gid >> 6] = -INFINITY;  /* kill exactly one */
    }
    if (lane == 0) out[pair] = scale[0] * (sum + bias[0]);
}

extern "C" void kernel_launch(void* const* d_in, const int* in_sizes, int n_in,
                              void* d_out, int out_size, void* d_ws, size_t ws_size,
                              hipStream_t stream) {
    const float* support = (const float*)d_in[0];
    const float* query   = (const float*)d_in[1];
    const float* scale   = (const float*)d_in[2];
    const float* bias    = (const float*)d_in[3];
    float* out = (float*)d_out;

    char* ws = (char*)d_ws;
    __hip_bfloat16* snw = (__hip_bfloat16*)ws;             /* 5*4*12*4*1024 = 983040 B */
    float* sinv         = (float*)(ws + 983040);           /* 980*4 -> pad to 4096 */
    float* rowmaxg      = (float*)(ws + 983040 + 4096);    /* 5*100352*4 = 2007040 */

    hipLaunchKernelGGL(k_norm0,   dim3(245),  dim3(256), 0, stream, support, sinv);
    hipLaunchKernelGGL(k_swz,     dim3(240),  dim3(256), 0, stream, support, sinv, snw);
    hipLaunchKernelGGL(k_gemm_max,dim3(NRB),  dim3(256), 0, stream, query, snw, rowmaxg);
    hipLaunchKernelGGL(k_top6,    dim3(640),  dim3(256), 0, stream, rowmaxg, scale, bias, out);
}